// Round 15
// baseline (111.811 us; speedup 1.0000x reference)
//
#include <hip/hip_runtime.h>
#include <hip/hip_bf16.h>

typedef __attribute__((ext_vector_type(4))) float f32x4;
typedef __attribute__((ext_vector_type(8))) short s16x8;
typedef __attribute__((ext_vector_type(4))) uint u32x4;

#define MFMA16(a, b, c) __builtin_amdgcn_mfma_f32_16x16x32_bf16(a, b, c, 0, 0, 0)

#define DG 256
#define NE 16
#define NN 17
#define TB 32      // tokens per block (two 16-row sub-batches)
#define NTOK 8192
#define PADU 264   // ushort row stride (528 B, 16B-aligned)

// ws offsets
#define WS_EW   8768     // exp@W1 [16][256] floats
#define FB_WMH  65536
#define FB_W1H  1114112
#define FB_W2H  1376256
#define WS_NEED 1638400

// ---------- scalar RNE helper ----------
__device__ __forceinline__ ushort bf16h(float f) {
    union { float f; uint u; } c; c.f = f;
    return (ushort)((c.u + 0x7fffu + ((c.u >> 16) & 1u)) >> 16);  // RNE
}

// ---------- fast packed converter (v_cvt_pk_bf16_f32) ----------
__device__ __forceinline__ uint pkbf(float a, float b) {
    __hip_bfloat162 t = __float22bfloat162_rn(make_float2(a, b));
    return *reinterpret_cast<uint*>(&t);
}

// W fragment: elem(l,i) = W[ks*32 + 8*(l>>4) + i][nt*16 + (l&15)]
template<bool SWZ>
__device__ __forceinline__ void loadBH(const ushort* __restrict__ H,
                                       const float* __restrict__ Wf,
                                       int KST, int nt, int ks, int lane,
                                       s16x8& bh) {
    if (SWZ) {
        bh = *(const s16x8*)(H + ((size_t)(nt * KST + ks) * 64 + lane) * 8);
    } else {
        const int k0 = ks * 32 + ((lane >> 4) << 3);
        const int col = nt * 16 + (lane & 15);
        const float* p = Wf + (size_t)k0 * DG + col;
#pragma unroll
        for (int i = 0; i < 8; ++i) bh[i] = (short)bf16h(p[(size_t)i * DG]);
    }
}

// -------- setup 1: blocks 0-15 expert path (-> ws EW); blocks 16+ weight swizzle --------
__global__ __launch_bounds__(512) void k_se1(const float* __restrict__ X,
                                             const float* __restrict__ Wst,
                                             const float* __restrict__ W1,
                                             const float* __restrict__ Wm,
                                             const float* __restrict__ W2,
                                             float* __restrict__ ws) {
    const int b = blockIdx.x, tid = threadIdx.x;
    if (b >= 16) {
        char* base = (char*)ws;
        const int base4 = (b - 16) * 2048 + tid * 4;
#pragma unroll
        for (int j = 0; j < 4; ++j) {
            const int local = base4 + j;
            const float* W; ushort* H; int lo2, KST;
            if (local < 262144)      { W = Wm; KST = 32; lo2 = local;          H = (ushort*)(base + FB_WMH); }
            else if (local < 327680) { W = W1; KST = 8;  lo2 = local - 262144; H = (ushort*)(base + FB_W1H); }
            else                     { W = W2; KST = 8;  lo2 = local - 327680; H = (ushort*)(base + FB_W2H); }
            const int i = lo2 & 7, l = (lo2 >> 3) & 63, t = lo2 >> 9;
            const int ks = t % KST, nt = t / KST;
            const int k = ks * 32 + ((l >> 4) << 3) + i;
            const int col = nt * 16 + (l & 15);
            H[lo2] = bf16h(W[(size_t)k * DG + col]);
        }
        return;
    }
    const int e = b;
    const int d = tid & 255, half = tid >> 8;
    __shared__ float xr[1024];
    __shared__ float part[2][256];
    __shared__ float er[256];

    *(float2*)&xr[tid * 2] = *(const float2*)&X[e * 1024 + tid * 2];
    __syncthreads();
    float acc = 0.f;
    const int k0 = half * 512;
    for (int k = 0; k < 512; ++k)
        acc = fmaf(xr[k0 + k], Wst[(size_t)(k0 + k) * DG + d], acc);
    part[half][d] = acc;
    __syncthreads();
    if (tid < 256) er[tid] = fmaxf(part[0][tid] + part[1][tid], 0.f);
    __syncthreads();
    float a2 = 0.f;
    const int m0 = half * 128;
    for (int m = 0; m < 128; ++m)
        a2 = fmaf(er[m0 + m], W1[(size_t)(m0 + m) * DG + d], a2);
    part[half][d] = a2;
    __syncthreads();
    if (tid < 256) ws[WS_EW + e * DG + tid] = part[0][tid] + part[1][tid];
}

// -------- fused main: TB=32, grid=256; in-block Sdiv/Ad2/mask setup; r13 phase-C body --------
template<bool SWZ>
__global__ __launch_bounds__(1024) void k_main(
        const float* __restrict__ x,
        const float* __restrict__ Wm,
        const float* __restrict__ W1,
        const float* __restrict__ W2,
        const float* __restrict__ Wp,
        const float* __restrict__ adj,
        const float* __restrict__ ws,
        float* __restrict__ out) {
    const int tid = threadIdx.x;
    const int lane = tid & 63, w = tid >> 6;          // wave = d-col-tile 0..15 (phase C/E)
    const int r16 = lane & 15, g4 = lane >> 4;
    const size_t t0 = (size_t)blockIdx.x * TB;

    __shared__ ushort S_bf[NN][PADU];                 // 8976 B (Sdiv bf16)
    __shared__ ushort g_bf[TB][PADU];                 // 16896 B (g bf16, 32 tokens)
    __shared__ alignas(16) union {
        ushort xs[2][8][2][64][8];                    // 32768 B (x frags, dbuf, 32 rows)
        ushort hfH[8][2][64][8];                      // 16384 B (h frags, M=32)
    } U1;
    __shared__ alignas(16) union {
        ushort frag[2][NN * 64 * 8];                  // 34816 B (y1 dbuf)
        float part[16][16][17];                       // 17408 B (aliases frag[0] only)
    } U2;
    __shared__ float Ad_l[NN * NN];
    __shared__ float dinv_s[NN];

    // staging map: thread -> (row 0..31, 8-float segment) of the 32x256 x-chunk
    const int srow = tid >> 5;
    const int s8 = tid & 31;
    const int sk8 = s8 >> 2;
    const int sl = ((s8 & 3) << 4) | (srow & 15);
    const int smt = srow >> 4;

    // ---- in-block setup stage 0: raw adj -> Ad_l, degrees, x chunk 0 ----
    float ad_raw = 0.f;
    if (tid < NN * NN) {
        ad_raw = adj[tid];
        Ad_l[tid] = ad_raw;
    }
    if (tid < NN) {
        float deg = 0.f;
        for (int m = 0; m < NN; ++m) deg += adj[tid * NN + m];
        dinv_s[tid] = 1.0f / sqrtf(deg);
    }
    {
        const float* px = &x[(t0 + srow) * 1024 + s8 * 8];
        const f32x4 v0 = *(const f32x4*)px;
        const f32x4 v1 = *(const f32x4*)(px + 4);
        u32x4 uu;
        uu[0] = pkbf(v0[0], v0[1]); uu[1] = pkbf(v0[2], v0[3]);
        uu[2] = pkbf(v1[0], v1[1]); uu[3] = pkbf(v1[2], v1[3]);
        *(u32x4*)&U1.xs[0][sk8][smt][sl][0] = uu;
    }
    __syncthreads();   // B1: Ad_l(raw), dinv, xs[0] ready

    // ---- in-block setup stage 1: Sdiv = (sum_e adj[n][e]*dinv[e]*ew[e][d]) / dinv[16] ----
    {
        const float inv_d16 = 1.0f / dinv_s[16];
        for (int j = tid; j < NN * DG; j += 1024) {
            const int n = j >> 8, d = j & 255;
            float s = 0.f;
#pragma unroll
            for (int e = 0; e < NE; ++e) {
                const float av = Ad_l[n * NN + e];
                if (av != 0.f)
                    s = fmaf(av * dinv_s[e], ws[WS_EW + e * DG + d], s);
            }
            S_bf[n][d] = bf16h(s * inv_d16);
        }
    }
    // Ad2 value in register (written to LDS after phase A's barriers)
    float ad2v = 0.f;
    if (tid < NN * NN) {
        const int rr = tid / NN, cc = tid % NN;
        ad2v = ad_raw * dinv_s[rr] * dinv_s[cc] * dinv_s[cc] * dinv_s[16];
    }

    const char* base = (const char*)ws;
    const ushort* WmH = (const ushort*)(base + FB_WMH);
    const ushort* W1H = (const ushort*)(base + FB_W1H);
    const ushort* W2H = (const ushort*)(base + FB_W2H);

    // ---- phase A: h = relu(x @ Wm), M=32; 8 waves x 2 d-tiles; 4 chunks, dbuf ----
    f32x4 hacc[2][2];
#pragma unroll
    for (int mt = 0; mt < 2; ++mt)
#pragma unroll
        for (int j = 0; j < 2; ++j) hacc[mt][j] = (f32x4){0.f, 0.f, 0.f, 0.f};

    for (int c = 0; c < 4; ++c) {
        f32x4 xn0, xn1;
        if (c < 3) {
            const float* px = &x[(t0 + srow) * 1024 + (c + 1) * 256 + s8 * 8];
            xn0 = *(const f32x4*)px;
            xn1 = *(const f32x4*)(px + 4);
        }
        if (w < 8) {
            for (int k8 = 0; k8 < 8; ++k8) {
                s16x8 bh0, bh1;
                loadBH<SWZ>(WmH, Wm, 32, 2 * w,     c * 8 + k8, lane, bh0);
                loadBH<SWZ>(WmH, Wm, 32, 2 * w + 1, c * 8 + k8, lane, bh1);
#pragma unroll
                for (int mt = 0; mt < 2; ++mt) {
                    const s16x8 ah = *(const s16x8*)&U1.xs[c & 1][k8][mt][lane][0];
                    hacc[mt][0] = MFMA16(ah, bh0, hacc[mt][0]);
                    hacc[mt][1] = MFMA16(ah, bh1, hacc[mt][1]);
                }
            }
        }
        if (c < 3) {
            u32x4 uu;
            uu[0] = pkbf(xn0[0], xn0[1]); uu[1] = pkbf(xn0[2], xn0[3]);
            uu[2] = pkbf(xn1[0], xn1[1]); uu[3] = pkbf(xn1[2], xn1[3]);
            *(u32x4*)&U1.xs[(c + 1) & 1][sk8][smt][sl][0] = uu;
        }
        __syncthreads();
    }

    // Ad2 in-place write (raw Ad_l reads all finished before phase A's first barrier)
    if (tid < NN * NN) Ad_l[tid] = ad2v;

    // write h (relu, single bf16) as M=32 MFMA A-fragments (xs dead, post-barrier)
    if (w < 8) {
#pragma unroll
        for (int mt = 0; mt < 2; ++mt)
#pragma unroll
            for (int j = 0; j < 2; ++j) {
                const uint p01 = pkbf(fmaxf(hacc[mt][j][0], 0.f), fmaxf(hacc[mt][j][1], 0.f));
                const uint p23 = pkbf(fmaxf(hacc[mt][j][2], 0.f), fmaxf(hacc[mt][j][3], 0.f));
                const int lb = ((2 * j + (r16 >> 3)) << 4) | (g4 * 4);
                const int ih = r16 & 7;
                U1.hfH[w][mt][lb + 0][ih] = (ushort)p01;
                U1.hfH[w][mt][lb + 1][ih] = (ushort)(p01 >> 16);
                U1.hfH[w][mt][lb + 2][ih] = (ushort)p23;
                U1.hfH[w][mt][lb + 3][ih] = (ushort)(p23 >> 16);
            }
    }
    __syncthreads();   // B: hfH + Ad2 ready

    // masks from Ad2 (uniform LDS broadcasts) -> SGPRs
    uint msk[NE];
#pragma unroll
    for (int e = 0; e < NE; ++e) {
        uint m = 0;
        for (int cth = 0; cth < NN; ++cth)
            if (Ad_l[e * NN + cth] != 0.f) m |= (1u << cth);
        msk[e] = __builtin_amdgcn_readfirstlane(m);
    }

    // ---- phase B: g = h @ W1 (both single bf16), M=32; 8 waves x 2 d-tiles ----
    if (w < 8) {
        f32x4 gacc[2][2];
#pragma unroll
        for (int mt = 0; mt < 2; ++mt)
#pragma unroll
            for (int j = 0; j < 2; ++j) gacc[mt][j] = (f32x4){0.f, 0.f, 0.f, 0.f};
        for (int k8 = 0; k8 < 8; ++k8) {
            s16x8 bh0, bh1;
            loadBH<SWZ>(W1H, W1, 8, 2 * w,     k8, lane, bh0);
            loadBH<SWZ>(W1H, W1, 8, 2 * w + 1, k8, lane, bh1);
#pragma unroll
            for (int mt = 0; mt < 2; ++mt) {
                const s16x8 ah = *(const s16x8*)&U1.hfH[k8][mt][lane][0];
                gacc[mt][0] = MFMA16(ah, bh0, gacc[mt][0]);
                gacc[mt][1] = MFMA16(ah, bh1, gacc[mt][1]);
            }
        }
#pragma unroll
        for (int mt = 0; mt < 2; ++mt)
#pragma unroll
            for (int j = 0; j < 2; ++j) {
                const uint q01 = pkbf(gacc[mt][j][0], gacc[mt][j][1]);
                const uint q23 = pkbf(gacc[mt][j][2], gacc[mt][j][3]);
                const int col = (2 * w + j) * 16 + r16;
                const int row0 = mt * 16 + g4 * 4;
                g_bf[row0 + 0][col] = (ushort)q01;
                g_bf[row0 + 1][col] = (ushort)(q01 >> 16);
                g_bf[row0 + 2][col] = (ushort)q23;
                g_bf[row0 + 3][col] = (ushort)(q23 >> 16);
            }
    }
    __syncthreads();   // g ready

    // ---- phases C+E per 16-token sub-batch (r13 body, no lookahead) ----
    const int bl_ = tid & 63;
    const int bn_ = tid >> 6;
    const int koff0 = (bl_ >> 4) << 3;
    const ushort* sB0 = &S_bf[bn_][koff0];
    const ushort* sB1 = &S_bf[16][koff0];
    ushort* const fr0a = U2.frag[0] + (size_t)tid * 8;
    ushort* const fr1a = U2.frag[1] + (size_t)tid * 8;
    ushort* const fr0b = U2.frag[0] + (size_t)(tid + 1024) * 8;
    ushort* const fr1b = U2.frag[1] + (size_t)(tid + 1024) * 8;
    const float wp = Wp[w * 16 + r16];
    const bool b0 = (r16 & 1) != 0;

    for (int sb = 0; sb < 2; ++sb) {
        const ushort* gB = &g_bf[sb * 16 + (bl_ & 15)][koff0];

        f32x4 acc[NN];
#pragma unroll
        for (int n = 0; n < NN; ++n) acc[n] = (f32x4){0.f, 0.f, 0.f, 0.f};

        for (int ks = 0; ks < 8; ++ks) {
            s16x8 bh;
            loadBH<SWZ>(W2H, W2, 8, w, ks, lane, bh);

            const int ko = ks * 32;
            const u32x4 gU = *(const u32x4*)(gB + ko);
            {
                const u32x4 sU = *(const u32x4*)(sB0 + ko);
                u32x4 uu;
#pragma unroll
                for (int i = 0; i < 4; ++i) {
                    union { uint u; float f; } gl, gh, sl2, sh;
                    gl.u = gU[i] << 16;  gh.u = gU[i] & 0xffff0000u;
                    sl2.u = sU[i] << 16; sh.u = sU[i] & 0xffff0000u;
                    uu[i] = pkbf(fmaxf(gl.f + sl2.f, 0.f), fmaxf(gh.f + sh.f, 0.f));
                }
                *(u32x4*)((ks & 1) ? fr1a : fr0a) = uu;
            }
            if (tid < 64) {   // hub node 16 (shares gU)
                const u32x4 sU = *(const u32x4*)(sB1 + ko);
                u32x4 uu;
#pragma unroll
                for (int i = 0; i < 4; ++i) {
                    union { uint u; float f; } gl, gh, sl2, sh;
                    gl.u = gU[i] << 16;  gh.u = gU[i] & 0xffff0000u;
                    sl2.u = sU[i] << 16; sh.u = sU[i] & 0xffff0000u;
                    uu[i] = pkbf(fmaxf(gl.f + sl2.f, 0.f), fmaxf(gh.f + sh.f, 0.f));
                }
                *(u32x4*)((ks & 1) ? fr1b : fr0b) = uu;
            }
            __syncthreads();   // frag[ks&1] ready; dbuf makes one barrier/ks hazard-safe

            const ushort* fb = U2.frag[ks & 1];
            __builtin_amdgcn_s_setprio(1);
#pragma unroll
            for (int n = 0; n < NN; ++n) {
                const s16x8 ah = *(const s16x8*)&fb[(n * 64 + lane) * 8];
                acc[n] = MFMA16(ah, bh, acc[n]);
            }
            __builtin_amdgcn_s_setprio(0);
        }
        // ks=7 read frag[1]; part aliases frag[0] (last read ks=6, behind ks=7's barrier) -> safe

        // ---- phase E: y2 = relu(Ad2 @ z); score = y2 . Wp; masked scan + pair butterfly ----
#pragma unroll
        for (int p = 0; p < 8; ++p) {
            f32x4 v2[2];
#pragma unroll
            for (int j = 0; j < 2; ++j) {
                const int e = 2 * p + j;
                f32x4 z = (f32x4){0.f, 0.f, 0.f, 0.f};
#pragma unroll
                for (int m = 0; m < NN; ++m) {
                    if (msk[e] & (1u << m)) {          // SGPR test -> scalar branch
                        const float av = Ad_l[e * NN + m];
#pragma unroll
                        for (int r = 0; r < 4; ++r) z[r] = fmaf(av, acc[m][r], z[r]);
                    }
                }
#pragma unroll
                for (int r = 0; r < 4; ++r) v2[j][r] = fmaxf(z[r], 0.f) * wp;
            }
            f32x4 wv;
#pragma unroll
            for (int r = 0; r < 4; ++r) {
                const float keep = b0 ? v2[1][r] : v2[0][r];
                const float send = b0 ? v2[0][r] : v2[1][r];
                wv[r] = keep + __shfl_xor(send, 1, 64);
            }
#pragma unroll
            for (int r = 0; r < 4; ++r) wv[r] += __shfl_xor(wv[r], 2, 64);
#pragma unroll
            for (int r = 0; r < 4; ++r) wv[r] += __shfl_xor(wv[r], 4, 64);
#pragma unroll
            for (int r = 0; r < 4; ++r) wv[r] += __shfl_xor(wv[r], 8, 64);
            if (r16 < 2)
#pragma unroll
                for (int r = 0; r < 4; ++r) U2.part[g4 * 4 + r][2 * p + r16][w] = wv[r];
        }
        __syncthreads();
        if (tid < 256) {
            const int t = tid >> 4, e = tid & 15;
            float s2 = 0.f;
#pragma unroll
            for (int q = 0; q < 16; ++q) s2 += U2.part[t][e][q];
            out[(t0 + sb * 16 + t) * NE + e] = s2;
        }
        __syncthreads();   // part reads done before next sb's build overwrites alias
    }
}

extern "C" void kernel_launch(void* const* d_in, const int* in_sizes, int n_in,
                              void* d_out, int out_size, void* d_ws, size_t ws_size,
                              hipStream_t stream) {
    const float* x   = (const float*)d_in[0];
    const float* X   = (const float*)d_in[1];
    const float* Wm  = (const float*)d_in[2];
    const float* Wst = (const float*)d_in[3];
    const float* Wc  = (const float*)d_in[4];
    const float* Wp  = (const float*)d_in[5];
    const float* adj = (const float*)d_in[6];
    float* out = (float*)d_out;
    float* ws  = (float*)d_ws;
    const float* W1 = Wc;
    const float* W2 = Wc + DG * DG;

    if (ws_size >= (size_t)WS_NEED) {
        k_se1<<<16 + 192, 512, 0, stream>>>(X, Wst, W1, Wm, W2, ws);
        k_main<true><<<NTOK / TB, 1024, 0, stream>>>(x, Wm, W1, W2, Wp, adj, ws, out);
    } else {
        k_se1<<<16, 512, 0, stream>>>(X, Wst, W1, Wm, W2, ws);
        k_main<false><<<NTOK / TB, 1024, 0, stream>>>(x, Wm, W1, W2, Wp, adj, ws, out);
    }
}

// Round 16
// 100.691 us; speedup vs baseline: 1.1104x; 1.1104x over previous
//
#include <hip/hip_runtime.h>
#include <hip/hip_bf16.h>

typedef __attribute__((ext_vector_type(4))) float f32x4;
typedef __attribute__((ext_vector_type(8))) short s16x8;
typedef __attribute__((ext_vector_type(4))) uint u32x4;

#define MFMA16(a, b, c) __builtin_amdgcn_mfma_f32_16x16x32_bf16(a, b, c, 0, 0, 0)

#define DG 256
#define NE 16
#define NN 17
#define TB 16      // tokens per block
#define NTOK 8192
#define PADU 264   // ushort row stride (528 B, 16B-aligned)

// ws offsets
#define WS_AD   4376     // Ad2 dense [17*17] floats
#define WS_MSK  4704     // nonzero masks [16] (uint)
#define WS_EW   8768     // exp@W1 [16][256] floats
// Sdiv bf16 [17][256] lives at ws bytes 0..8704
#define FB_WMH  65536
#define FB_W1H  1114112
#define FB_W2H  1376256
#define WS_NEED 1638400

// ---------- scalar RNE helper ----------
__device__ __forceinline__ ushort bf16h(float f) {
    union { float f; uint u; } c; c.f = f;
    return (ushort)((c.u + 0x7fffu + ((c.u >> 16) & 1u)) >> 16);  // RNE
}

// ---------- fast packed converter (v_cvt_pk_bf16_f32) ----------
__device__ __forceinline__ uint pkbf(float a, float b) {
    __hip_bfloat162 t = __float22bfloat162_rn(make_float2(a, b));
    return *reinterpret_cast<uint*>(&t);
}

// W fragment: elem(l,i) = W[ks*32 + 8*(l>>4) + i][nt*16 + (l&15)]
template<bool SWZ>
__device__ __forceinline__ void loadBH(const ushort* __restrict__ H,
                                       const float* __restrict__ Wf,
                                       int KST, int nt, int ks, int lane,
                                       s16x8& bh) {
    if (SWZ) {
        bh = *(const s16x8*)(H + ((size_t)(nt * KST + ks) * 64 + lane) * 8);
    } else {
        const int k0 = ks * 32 + ((lane >> 4) << 3);
        const int col = nt * 16 + (lane & 15);
        const float* p = Wf + (size_t)k0 * DG + col;
#pragma unroll
        for (int i = 0; i < 8; ++i) bh[i] = (short)bf16h(p[(size_t)i * DG]);
    }
}

// -------- setup 1: blocks 0-15 expert path; blocks 16+ weight swizzle (single bf16) --------
__global__ __launch_bounds__(512) void k_se1(const float* __restrict__ X,
                                             const float* __restrict__ Wst,
                                             const float* __restrict__ W1,
                                             const float* __restrict__ Wm,
                                             const float* __restrict__ W2,
                                             float* __restrict__ ws) {
    const int b = blockIdx.x, tid = threadIdx.x;
    if (b >= 16) {
        char* base = (char*)ws;
        const int base4 = (b - 16) * 2048 + tid * 4;
#pragma unroll
        for (int j = 0; j < 4; ++j) {
            const int local = base4 + j;
            const float* W; ushort* H; int lo2, KST;
            if (local < 262144)      { W = Wm; KST = 32; lo2 = local;          H = (ushort*)(base + FB_WMH); }
            else if (local < 327680) { W = W1; KST = 8;  lo2 = local - 262144; H = (ushort*)(base + FB_W1H); }
            else                     { W = W2; KST = 8;  lo2 = local - 327680; H = (ushort*)(base + FB_W2H); }
            const int i = lo2 & 7, l = (lo2 >> 3) & 63, t = lo2 >> 9;
            const int ks = t % KST, nt = t / KST;
            const int k = ks * 32 + ((l >> 4) << 3) + i;
            const int col = nt * 16 + (l & 15);
            H[lo2] = bf16h(W[(size_t)k * DG + col]);
        }
        return;
    }
    const int e = b;
    const int d = tid & 255, half = tid >> 8;
    __shared__ float xr[1024];
    __shared__ float part[2][256];
    __shared__ float er[256];

    *(float2*)&xr[tid * 2] = *(const float2*)&X[e * 1024 + tid * 2];
    __syncthreads();
    float acc = 0.f;
    const int k0 = half * 512;
    for (int k = 0; k < 512; ++k)
        acc = fmaf(xr[k0 + k], Wst[(size_t)(k0 + k) * DG + d], acc);
    part[half][d] = acc;
    __syncthreads();
    if (tid < 256) er[tid] = fmaxf(part[0][tid] + part[1][tid], 0.f);
    __syncthreads();
    float a2 = 0.f;
    const int m0 = half * 128;
    for (int m = 0; m < 128; ++m)
        a2 = fmaf(er[m0 + m], W1[(size_t)(m0 + m) * DG + d], a2);
    part[half][d] = a2;
    __syncthreads();
    if (tid < 256) ws[WS_EW + e * DG + tid] = part[0][tid] + part[1][tid];
}

// -------- setup 2 (18 blocks): 0-16 Sdiv rows (bf16); 17: Ad2 dense + nonzero masks --------
__global__ __launch_bounds__(256) void k_se2(const float* __restrict__ adj,
                                             float* __restrict__ ws) {
    const int b = blockIdx.x, tid = threadIdx.x;
    __shared__ float dinv[NN];
    __shared__ float row[NN];
    __shared__ float Ad_sh[NN * NN];
    if (tid < NN) {
        float deg = 0.f;
        for (int m = 0; m < NN; ++m) deg += adj[tid * NN + m];
        dinv[tid] = 1.0f / sqrtf(deg);
    }
    __syncthreads();
    if (b < NN) {
        if (tid < NN) row[tid] = adj[b * NN + tid] * dinv[b] * dinv[tid];
        __syncthreads();
        float s = 0.f;
        for (int e = 0; e < NE; ++e) s = fmaf(row[e], ws[WS_EW + e * DG + tid], s);
        const float ab = dinv[b] * dinv[16];   // a[b] > 0 (hub column all-ones)
        ((ushort*)ws)[b * 256 + tid] = bf16h(s / ab);
    } else {
        for (int i = tid; i < NN * NN; i += 256) {
            const int r = i / NN, c = i % NN;
            Ad_sh[i] = adj[i] * dinv[r] * dinv[c] * dinv[c] * dinv[16];
        }
        __syncthreads();
        for (int i = tid; i < NN * NN; i += 256) ws[WS_AD + i] = Ad_sh[i];
        if (tid < NE) {
            uint m = 0;
            for (int c = 0; c < NN; ++c)
                if (Ad_sh[tid * NN + c] != 0.f) m |= (1u << c);
            ((uint*)(ws))[WS_MSK + tid] = m;
        }
    }
}

// -------- fused main: TB=16, 1024 thr, 16 waves; PREBUILT fragAll -> barrier-free consume --------
template<bool SWZ>
__global__ __launch_bounds__(1024) void k_main(
        const float* __restrict__ x,
        const float* __restrict__ Wm,
        const float* __restrict__ W1,
        const float* __restrict__ W2,
        const float* __restrict__ Wp,
        const float* __restrict__ ws,
        float* __restrict__ out) {
    const int tid = threadIdx.x;
    const int lane = tid & 63, w = tid >> 6;          // wave = d-col-tile 0..15 (phase C/E)
    const int r16 = lane & 15, g4 = lane >> 4;
    const size_t t0 = (size_t)blockIdx.x * TB;

    __shared__ ushort S_bf[NN][PADU];                 // 8976 B (Sdiv bf16)
    __shared__ ushort g_bf[TB][PADU];                 // 8448 B (g bf16)
    __shared__ alignas(16) union {
        ushort xs[2][8][64][8];                       // 16384 B (x frags, dbuf)
        ushort hfH[8][64][8];                         // 8192 B (h frags)
        ushort fragAll[NN * 512 * 8];                 // 139264 B (y1, all 8 ks)
        float part[16][16][17];                       // 17408 B (aliases fragAll head)
    } U;
    __shared__ float Ad_l[NN * NN];

    // staging map: thread -> (row, 4-float segment) of the 16x256 x-chunk
    const int srow = tid >> 6;                        // 0..15
    const int sseg = tid & 63;
    const int sk8 = sseg >> 3;
    const int so  = (sseg * 4) & 31;
    const int sl  = ((so >> 3) << 4) | srow;
    const int si  = so & 7;                           // 0 or 4

    // load Sdiv (bf16 pairs) + Ad
    for (int j = tid; j < NN * 128; j += 1024)
        *(uint*)&S_bf[j >> 7][(j & 127) << 1] = ((const uint*)ws)[j];
    for (int j = tid; j < NN * NN; j += 1024) Ad_l[j] = ws[WS_AD + j];

    // hoist nonzero masks into SGPRs
    uint msk[NE];
#pragma unroll
    for (int e = 0; e < NE; ++e)
        msk[e] = __builtin_amdgcn_readfirstlane(((const uint*)ws)[WS_MSK + e]);

    const char* base = (const char*)ws;
    const ushort* WmH = (const ushort*)(base + FB_WMH);
    const ushort* W1H = (const ushort*)(base + FB_W1H);
    const ushort* W2H = (const ushort*)(base + FB_W2H);

    // stage x chunk 0 (single bf16, convert-once)
    {
        const f32x4 v = *(const f32x4*)&x[(t0 + srow) * 1024 + sseg * 4];
        uint2 uu = make_uint2(pkbf(v[0], v[1]), pkbf(v[2], v[3]));
        *(uint2*)&U.xs[0][sk8][sl][si] = uu;
    }
    __syncthreads();

    // ---- phase A: h = relu(x @ Wm); 8 waves x 2 col-tiles; 4 chunks, dbuf ----
    f32x4 hacc[2];
    hacc[0] = (f32x4){0.f, 0.f, 0.f, 0.f};
    hacc[1] = (f32x4){0.f, 0.f, 0.f, 0.f};
    for (int c = 0; c < 4; ++c) {
        f32x4 xn;
        if (c < 3)
            xn = *(const f32x4*)&x[(t0 + srow) * 1024 + (c + 1) * 256 + sseg * 4];
        if (w < 8) {
            for (int k8 = 0; k8 < 8; ++k8) {
                s16x8 bh0, bh1;
                loadBH<SWZ>(WmH, Wm, 32, 2 * w,     c * 8 + k8, lane, bh0);
                loadBH<SWZ>(WmH, Wm, 32, 2 * w + 1, c * 8 + k8, lane, bh1);
                const s16x8 ah = *(const s16x8*)&U.xs[c & 1][k8][lane][0];
                hacc[0] = MFMA16(ah, bh0, hacc[0]);
                hacc[1] = MFMA16(ah, bh1, hacc[1]);
            }
        }
        if (c < 3) {
            uint2 uu = make_uint2(pkbf(xn[0], xn[1]), pkbf(xn[2], xn[3]));
            *(uint2*)&U.xs[(c + 1) & 1][sk8][sl][si] = uu;
        }
        __syncthreads();
    }

    // write h (relu, single bf16) as MFMA A-fragments (xs dead, post-barrier)
    if (w < 8) {
#pragma unroll
        for (int j = 0; j < 2; ++j) {
            const int c2 = 2 * w + j;
            const int k8h = c2 >> 1;                  // = w
            const int o = ((c2 & 1) << 4) | r16;
            const int lb = (o >> 3) << 4;
            const int ih = o & 7;
            const uint p01 = pkbf(fmaxf(hacc[j][0], 0.f), fmaxf(hacc[j][1], 0.f));
            const uint p23 = pkbf(fmaxf(hacc[j][2], 0.f), fmaxf(hacc[j][3], 0.f));
            const int r0 = g4 * 4;
            U.hfH[k8h][lb + r0 + 0][ih] = (ushort)p01;
            U.hfH[k8h][lb + r0 + 1][ih] = (ushort)(p01 >> 16);
            U.hfH[k8h][lb + r0 + 2][ih] = (ushort)p23;
            U.hfH[k8h][lb + r0 + 3][ih] = (ushort)(p23 >> 16);
        }
    }
    __syncthreads();

    // ---- phase B: g = h @ W1 (both single bf16); 8 waves x 2 tiles ----
    if (w < 8) {
        f32x4 gacc[2];
        gacc[0] = (f32x4){0.f, 0.f, 0.f, 0.f};
        gacc[1] = (f32x4){0.f, 0.f, 0.f, 0.f};
        for (int k8 = 0; k8 < 8; ++k8) {
            s16x8 bh0, bh1;
            loadBH<SWZ>(W1H, W1, 8, 2 * w,     k8, lane, bh0);
            loadBH<SWZ>(W1H, W1, 8, 2 * w + 1, k8, lane, bh1);
            const s16x8 ah = *(const s16x8*)&U.hfH[k8][lane][0];
            gacc[0] = MFMA16(ah, bh0, gacc[0]);
            gacc[1] = MFMA16(ah, bh1, gacc[1]);
        }
#pragma unroll
        for (int j = 0; j < 2; ++j) {
            const uint q01 = pkbf(gacc[j][0], gacc[j][1]);
            const uint q23 = pkbf(gacc[j][2], gacc[j][3]);
            const int col = (2 * w + j) * 16 + r16;
            g_bf[g4 * 4 + 0][col] = (ushort)q01;
            g_bf[g4 * 4 + 1][col] = (ushort)(q01 >> 16);
            g_bf[g4 * 4 + 2][col] = (ushort)q23;
            g_bf[g4 * 4 + 3][col] = (ushort)(q23 >> 16);
        }
    }
    __syncthreads();   // g ready; hfH reads done (fragAll overlays hfH next)

    // ---- phase C prebuild: ALL 8 ks y1 fragments -> fragAll[n][ks][64] ----
    // slot j = n*512 + ks*64 + l ; y1 = relu(g[l&15][k] + Sdiv[n][k]), k = ks*32+8*(l>>4)..
    for (int j = tid; j < NN * 512; j += 1024) {
        const int n = j >> 9;
        const int l = j & 63;
        const int k0 = ((j >> 6) & 7) * 32 + ((l >> 4) << 3);
        const u32x4 gU = *(const u32x4*)&g_bf[l & 15][k0];
        const u32x4 sU = *(const u32x4*)&S_bf[n][k0];
        u32x4 uu;
#pragma unroll
        for (int i = 0; i < 4; ++i) {
            union { uint u; float f; } gl, gh, sl2, sh;
            gl.u = gU[i] << 16;  gh.u = gU[i] & 0xffff0000u;
            sl2.u = sU[i] << 16; sh.u = sU[i] & 0xffff0000u;
            uu[i] = pkbf(fmaxf(gl.f + sl2.f, 0.f), fmaxf(gh.f + sh.f, 0.f));
        }
        *(u32x4*)&U.fragAll[(size_t)j * 8] = uu;
    }
    __syncthreads();   // fragAll ready; read-only below -> NO barriers in consume loop

    // ---- phase C consume: 8 ks x 17 MFMA, barrier-free ----
    f32x4 acc[NN];
#pragma unroll
    for (int n = 0; n < NN; ++n) acc[n] = (f32x4){0.f, 0.f, 0.f, 0.f};

#pragma unroll 1
    for (int ks = 0; ks < 8; ++ks) {
        s16x8 bh;
        loadBH<SWZ>(W2H, W2, 8, w, ks, lane, bh);
        __builtin_amdgcn_s_setprio(1);
#pragma unroll
        for (int n = 0; n < NN; ++n) {
            const s16x8 ah = *(const s16x8*)&U.fragAll[(size_t)((n * 8 + ks) * 64 + lane) * 8];
            acc[n] = MFMA16(ah, bh, acc[n]);
        }
        __builtin_amdgcn_s_setprio(0);
    }
    __syncthreads();   // all fragAll reads done before part (aliases head) is written

    // ---- phase E: y2 = relu(Ad2 @ z); score = y2 . Wp; masked scan + pair butterfly ----
    const float wp = Wp[w * 16 + r16];
    const bool b0 = (r16 & 1) != 0;
#pragma unroll
    for (int p = 0; p < 8; ++p) {
        f32x4 v2[2];
#pragma unroll
        for (int j = 0; j < 2; ++j) {
            const int e = 2 * p + j;
            f32x4 z = (f32x4){0.f, 0.f, 0.f, 0.f};
#pragma unroll
            for (int m = 0; m < NN; ++m) {
                if (msk[e] & (1u << m)) {          // SGPR test -> scalar branch
                    const float av = Ad_l[e * NN + m];
#pragma unroll
                    for (int r = 0; r < 4; ++r) z[r] = fmaf(av, acc[m][r], z[r]);
                }
            }
#pragma unroll
            for (int r = 0; r < 4; ++r) v2[j][r] = fmaxf(z[r], 0.f) * wp;
        }
        f32x4 wv;
#pragma unroll
        for (int r = 0; r < 4; ++r) {
            const float keep = b0 ? v2[1][r] : v2[0][r];
            const float send = b0 ? v2[0][r] : v2[1][r];
            wv[r] = keep + __shfl_xor(send, 1, 64);
        }
#pragma unroll
        for (int r = 0; r < 4; ++r) wv[r] += __shfl_xor(wv[r], 2, 64);
#pragma unroll
        for (int r = 0; r < 4; ++r) wv[r] += __shfl_xor(wv[r], 4, 64);
#pragma unroll
        for (int r = 0; r < 4; ++r) wv[r] += __shfl_xor(wv[r], 8, 64);
        if (r16 < 2)
#pragma unroll
            for (int r = 0; r < 4; ++r) U.part[g4 * 4 + r][2 * p + r16][w] = wv[r];
    }
    __syncthreads();
    if (tid < 256) {
        const int t = tid >> 4, e = tid & 15;
        float s2 = 0.f;
#pragma unroll
        for (int q = 0; q < 16; ++q) s2 += U.part[t][e][q];
        out[(t0 + t) * NE + e] = s2;
    }
}

extern "C" void kernel_launch(void* const* d_in, const int* in_sizes, int n_in,
                              void* d_out, int out_size, void* d_ws, size_t ws_size,
                              hipStream_t stream) {
    const float* x   = (const float*)d_in[0];
    const float* X   = (const float*)d_in[1];
    const float* Wm  = (const float*)d_in[2];
    const float* Wst = (const float*)d_in[3];
    const float* Wc  = (const float*)d_in[4];
    const float* Wp  = (const float*)d_in[5];
    const float* adj = (const float*)d_in[6];
    float* out = (float*)d_out;
    float* ws  = (float*)d_ws;
    const float* W1 = Wc;
    const float* W2 = Wc + DG * DG;

    if (ws_size >= (size_t)WS_NEED) {
        k_se1<<<16 + 192, 512, 0, stream>>>(X, Wst, W1, Wm, W2, ws);
        k_se2<<<18, 256, 0, stream>>>(adj, ws);
        k_main<true><<<NTOK / TB, 1024, 0, stream>>>(x, Wm, W1, W2, Wp, ws, out);
    } else {
        k_se1<<<16, 512, 0, stream>>>(X, Wst, W1, Wm, W2, ws);
        k_se2<<<18, 256, 0, stream>>>(adj, ws);
        k_main<false><<<NTOK / TB, 1024, 0, stream>>>(x, Wm, W1, W2, Wp, ws, out);
    }
}

// Round 17
// 96.802 us; speedup vs baseline: 1.1550x; 1.0402x over previous
//
#include <hip/hip_runtime.h>
#include <hip/hip_bf16.h>

typedef __attribute__((ext_vector_type(4))) float f32x4;
typedef __attribute__((ext_vector_type(16))) float f32x16;
typedef __attribute__((ext_vector_type(8))) short s16x8;
typedef __attribute__((ext_vector_type(4))) uint u32x4;

#define MFMA16(a, b, c) __builtin_amdgcn_mfma_f32_16x16x32_bf16(a, b, c, 0, 0, 0)
#define MFMA32(a, b, c) __builtin_amdgcn_mfma_f32_32x32x16_bf16(a, b, c, 0, 0, 0)

#define DG 256
#define NE 16
#define NN 17
#define TB 16      // tokens per block
#define NTOK 8192
#define PADU 264   // ushort row stride (528 B, 16B-aligned)

// ws offsets
#define WS_AD   4376     // Ad2 dense [17*17] floats
#define WS_MSK  4704     // nonzero masks [16] (uint)
#define WS_EW   8768     // exp@W1 [16][256] floats
// Sdiv bf16 [17][256] lives at ws bytes 0..8704
#define FB_WMH  65536    // Wm 16-style frags (262144 ushort)
#define FB_W1H  1114112  // W1 16-style (65536)
#define FB_W2H  1376256  // W2 16-style (65536)
#define FB_W2X  1507328  // W2 32-style (65536)
#define WS_NEED 1638400

// ---------- scalar RNE helper ----------
__device__ __forceinline__ ushort bf16h(float f) {
    union { float f; uint u; } c; c.f = f;
    return (ushort)((c.u + 0x7fffu + ((c.u >> 16) & 1u)) >> 16);  // RNE
}

// ---------- fast packed converter (v_cvt_pk_bf16_f32) ----------
__device__ __forceinline__ uint pkbf(float a, float b) {
    __hip_bfloat162 t = __float22bfloat162_rn(make_float2(a, b));
    return *reinterpret_cast<uint*>(&t);
}

// 16-style W fragment: elem(l,i) = W[ks*32 + 8*(l>>4) + i][nt*16 + (l&15)]
template<bool SWZ>
__device__ __forceinline__ void loadBH(const ushort* __restrict__ H,
                                       const float* __restrict__ Wf,
                                       int KST, int nt, int ks, int lane,
                                       s16x8& bh) {
    if (SWZ) {
        bh = *(const s16x8*)(H + ((size_t)(nt * KST + ks) * 64 + lane) * 8);
    } else {
        const int k0 = ks * 32 + ((lane >> 4) << 3);
        const int col = nt * 16 + (lane & 15);
        const float* p = Wf + (size_t)k0 * DG + col;
#pragma unroll
        for (int i = 0; i < 8; ++i) bh[i] = (short)bf16h(p[(size_t)i * DG]);
    }
}

// 32-style W fragment: elem(l,i) = W[t*16 + 8*(l>>5) + i][wt*32 + (l&31)]
template<bool SWZ>
__device__ __forceinline__ void loadB32(const ushort* __restrict__ H,
                                        const float* __restrict__ Wf,
                                        int wt, int t, int lane, s16x8& bh) {
    if (SWZ) {
        bh = *(const s16x8*)(H + ((size_t)(wt * 16 + t) * 64 + lane) * 8);
    } else {
        const int k0 = t * 16 + ((lane >> 5) << 3);
        const int col = wt * 32 + (lane & 31);
        const float* p = Wf + (size_t)k0 * DG + col;
#pragma unroll
        for (int i = 0; i < 8; ++i) bh[i] = (short)bf16h(p[(size_t)i * DG]);
    }
}

// -------- setup 1: blocks 0-15 expert path; blocks 16+ weight swizzle --------
__global__ __launch_bounds__(512) void k_se1(const float* __restrict__ X,
                                             const float* __restrict__ Wst,
                                             const float* __restrict__ W1,
                                             const float* __restrict__ Wm,
                                             const float* __restrict__ W2,
                                             float* __restrict__ ws) {
    const int b = blockIdx.x, tid = threadIdx.x;
    if (b >= 16) {
        char* base = (char*)ws;
        const int base4 = (b - 16) * 2048 + tid * 4;
#pragma unroll
        for (int j = 0; j < 4; ++j) {
            const int local = base4 + j;
            if (local < 393216) {
                const float* W; ushort* H; int lo2, KST;
                if (local < 262144)      { W = Wm; KST = 32; lo2 = local;          H = (ushort*)(base + FB_WMH); }
                else if (local < 327680) { W = W1; KST = 8;  lo2 = local - 262144; H = (ushort*)(base + FB_W1H); }
                else                     { W = W2; KST = 8;  lo2 = local - 327680; H = (ushort*)(base + FB_W2H); }
                const int i = lo2 & 7, l = (lo2 >> 3) & 63, t = lo2 >> 9;
                const int ks = t % KST, nt = t / KST;
                const int k = ks * 32 + ((l >> 4) << 3) + i;
                const int col = nt * 16 + (l & 15);
                H[lo2] = bf16h(W[(size_t)k * DG + col]);
            } else {   // W2 32-style
                ushort* H = (ushort*)(base + FB_W2X);
                const int lo2 = local - 393216;
                const int i = lo2 & 7, l = (lo2 >> 3) & 63, t2 = lo2 >> 9;
                const int t = t2 & 15, wt = t2 >> 4;
                const int k = t * 16 + ((l >> 5) << 3) + i;
                const int col = wt * 32 + (l & 31);
                H[lo2] = bf16h(W2[(size_t)k * DG + col]);
            }
        }
        return;
    }
    const int e = b;
    const int d = tid & 255, half = tid >> 8;
    __shared__ float xr[1024];
    __shared__ float part[2][256];
    __shared__ float er[256];

    *(float2*)&xr[tid * 2] = *(const float2*)&X[e * 1024 + tid * 2];
    __syncthreads();
    float acc = 0.f;
    const int k0 = half * 512;
    for (int k = 0; k < 512; ++k)
        acc = fmaf(xr[k0 + k], Wst[(size_t)(k0 + k) * DG + d], acc);
    part[half][d] = acc;
    __syncthreads();
    if (tid < 256) er[tid] = fmaxf(part[0][tid] + part[1][tid], 0.f);
    __syncthreads();
    float a2 = 0.f;
    const int m0 = half * 128;
    for (int m = 0; m < 128; ++m)
        a2 = fmaf(er[m0 + m], W1[(size_t)(m0 + m) * DG + d], a2);
    part[half][d] = a2;
    __syncthreads();
    if (tid < 256) ws[WS_EW + e * DG + tid] = part[0][tid] + part[1][tid];
}

// -------- setup 2 (18 blocks): 0-16 Sdiv rows (bf16); 17: Ad2 dense + masks --------
__global__ __launch_bounds__(256) void k_se2(const float* __restrict__ adj,
                                             float* __restrict__ ws) {
    const int b = blockIdx.x, tid = threadIdx.x;
    __shared__ float dinv[NN];
    __shared__ float row[NN];
    __shared__ float Ad_sh[NN * NN];
    if (tid < NN) {
        float deg = 0.f;
        for (int m = 0; m < NN; ++m) deg += adj[tid * NN + m];
        dinv[tid] = 1.0f / sqrtf(deg);
    }
    __syncthreads();
    if (b < NN) {
        if (tid < NN) row[tid] = adj[b * NN + tid] * dinv[b] * dinv[tid];
        __syncthreads();
        float s = 0.f;
        for (int e = 0; e < NE; ++e) s = fmaf(row[e], ws[WS_EW + e * DG + tid], s);
        const float ab = dinv[b] * dinv[16];   // a[b] > 0 (hub column all-ones)
        ((ushort*)ws)[b * 256 + tid] = bf16h(s / ab);
    } else {
        for (int i = tid; i < NN * NN; i += 256) {
            const int r = i / NN, c = i % NN;
            Ad_sh[i] = adj[i] * dinv[r] * dinv[c] * dinv[c] * dinv[16];
        }
        __syncthreads();
        for (int i = tid; i < NN * NN; i += 256) ws[WS_AD + i] = Ad_sh[i];
        if (tid < NE) {
            uint m = 0;
            for (int c = 0; c < NN; ++c)
                if (Ad_sh[tid * NN + c] != 0.f) m |= (1u << c);
            ((uint*)(ws))[WS_MSK + tid] = m;
        }
    }
}

// -------- fused main: TB=16, 512 thr, 8 waves; 32x32 MFMA phase C --------
template<bool SWZ>
__global__ __launch_bounds__(512) void k_main(
        const float* __restrict__ x,
        const float* __restrict__ Wm,
        const float* __restrict__ W1,
        const float* __restrict__ W2,
        const float* __restrict__ Wp,
        const float* __restrict__ ws,
        float* __restrict__ out) {
    const int tid = threadIdx.x;
    const int lane = tid & 63, w = tid >> 6;          // wave = 32-col d-tile 0..7
    const int r16 = lane & 15, g4 = lane >> 4;
    const size_t t0 = (size_t)blockIdx.x * TB;

    __shared__ ushort S_bf[NN][PADU];                 // 8976 B (Sdiv bf16)
    __shared__ ushort g_bf[TB][PADU];                 // 8448 B
    __shared__ alignas(16) union {
        ushort xs[2][8][64][8];                       // 16384 B (x frags, dbuf)
        ushort hfH[8][64][8];                         // 8192 B (h frags)
        ushort fragAll[8 * 16 * 64 * 8];              // 131072 B (y1 pairs, all 16 t)
        float part[16][16][9];                        // 9216 B (aliases fragAll head)
    } U;
    __shared__ ushort frag16[8 * 64 * 8];             // 8192 B (node-16 y1, 16-style)
    __shared__ float Ad_l[NN * NN];                   // 1156 B

    // staging map: thread -> (row, 8-float segment) of the 16x256 x-chunk
    const int srow = tid >> 5;                        // 0..15
    const int s8 = tid & 31;
    const int sk8 = s8 >> 2;
    const int sl = ((s8 & 3) << 4) | srow;

    // load Sdiv (bf16 pairs) + Ad
    for (int j = tid; j < NN * 128; j += 512)
        *(uint*)&S_bf[j >> 7][(j & 127) << 1] = ((const uint*)ws)[j];
    for (int j = tid; j < NN * NN; j += 512) Ad_l[j] = ws[WS_AD + j];

    uint msk[NE];
#pragma unroll
    for (int e = 0; e < NE; ++e)
        msk[e] = __builtin_amdgcn_readfirstlane(((const uint*)ws)[WS_MSK + e]);

    const char* base = (const char*)ws;
    const ushort* WmH = (const ushort*)(base + FB_WMH);
    const ushort* W1H = (const ushort*)(base + FB_W1H);
    const ushort* W2H = (const ushort*)(base + FB_W2H);
    const ushort* W2X = (const ushort*)(base + FB_W2X);

    // stage x chunk 0 (single bf16, convert-once; 8 floats/thread)
    {
        const float* px = &x[(t0 + srow) * 1024 + s8 * 8];
        const f32x4 v0 = *(const f32x4*)px;
        const f32x4 v1 = *(const f32x4*)(px + 4);
        u32x4 uu;
        uu[0] = pkbf(v0[0], v0[1]); uu[1] = pkbf(v0[2], v0[3]);
        uu[2] = pkbf(v1[0], v1[1]); uu[3] = pkbf(v1[2], v1[3]);
        *(u32x4*)&U.xs[0][sk8][sl][0] = uu;
    }
    __syncthreads();

    // ---- phase A: h = relu(x @ Wm); 8 waves x 2 col-tiles; 4 chunks, dbuf ----
    f32x4 hacc[2];
    hacc[0] = (f32x4){0.f, 0.f, 0.f, 0.f};
    hacc[1] = (f32x4){0.f, 0.f, 0.f, 0.f};
    for (int c = 0; c < 4; ++c) {
        f32x4 xn0, xn1;
        if (c < 3) {
            const float* px = &x[(t0 + srow) * 1024 + (c + 1) * 256 + s8 * 8];
            xn0 = *(const f32x4*)px;
            xn1 = *(const f32x4*)(px + 4);
        }
        for (int k8 = 0; k8 < 8; ++k8) {
            s16x8 bh0, bh1;
            loadBH<SWZ>(WmH, Wm, 32, 2 * w,     c * 8 + k8, lane, bh0);
            loadBH<SWZ>(WmH, Wm, 32, 2 * w + 1, c * 8 + k8, lane, bh1);
            const s16x8 ah = *(const s16x8*)&U.xs[c & 1][k8][lane][0];
            hacc[0] = MFMA16(ah, bh0, hacc[0]);
            hacc[1] = MFMA16(ah, bh1, hacc[1]);
        }
        if (c < 3) {
            u32x4 uu;
            uu[0] = pkbf(xn0[0], xn0[1]); uu[1] = pkbf(xn0[2], xn0[3]);
            uu[2] = pkbf(xn1[0], xn1[1]); uu[3] = pkbf(xn1[2], xn1[3]);
            *(u32x4*)&U.xs[(c + 1) & 1][sk8][sl][0] = uu;
        }
        __syncthreads();
    }

    // write h (relu, single bf16) as MFMA A-fragments (xs dead, post-barrier)
    {
#pragma unroll
        for (int j = 0; j < 2; ++j) {
            const int c2 = 2 * w + j;
            const int k8h = c2 >> 1;                  // = w
            const int o = ((c2 & 1) << 4) | r16;
            const int lb = (o >> 3) << 4;
            const int ih = o & 7;
            const uint p01 = pkbf(fmaxf(hacc[j][0], 0.f), fmaxf(hacc[j][1], 0.f));
            const uint p23 = pkbf(fmaxf(hacc[j][2], 0.f), fmaxf(hacc[j][3], 0.f));
            const int r0 = g4 * 4;
            U.hfH[k8h][lb + r0 + 0][ih] = (ushort)p01;
            U.hfH[k8h][lb + r0 + 1][ih] = (ushort)(p01 >> 16);
            U.hfH[k8h][lb + r0 + 2][ih] = (ushort)p23;
            U.hfH[k8h][lb + r0 + 3][ih] = (ushort)(p23 >> 16);
        }
    }
    __syncthreads();

    // ---- phase B: g = h @ W1 (both single bf16); 8 waves x 2 tiles ----
    {
        f32x4 gacc[2];
        gacc[0] = (f32x4){0.f, 0.f, 0.f, 0.f};
        gacc[1] = (f32x4){0.f, 0.f, 0.f, 0.f};
        for (int k8 = 0; k8 < 8; ++k8) {
            s16x8 bh0, bh1;
            loadBH<SWZ>(W1H, W1, 8, 2 * w,     k8, lane, bh0);
            loadBH<SWZ>(W1H, W1, 8, 2 * w + 1, k8, lane, bh1);
            const s16x8 ah = *(const s16x8*)&U.hfH[k8][lane][0];
            gacc[0] = MFMA16(ah, bh0, gacc[0]);
            gacc[1] = MFMA16(ah, bh1, gacc[1]);
        }
#pragma unroll
        for (int j = 0; j < 2; ++j) {
            const uint q01 = pkbf(gacc[j][0], gacc[j][1]);
            const uint q23 = pkbf(gacc[j][2], gacc[j][3]);
            const int col = (2 * w + j) * 16 + r16;
            g_bf[g4 * 4 + 0][col] = (ushort)q01;
            g_bf[g4 * 4 + 1][col] = (ushort)(q01 >> 16);
            g_bf[g4 * 4 + 2][col] = (ushort)q23;
            g_bf[g4 * 4 + 3][col] = (ushort)(q23 >> 16);
        }
    }
    __syncthreads();   // g ready; hfH reads done (fragAll overlays next)

    // ---- phase C prebuild: 8 node-pairs x 16 t (32x32 A-frags) + node16 (16-style) ----
    for (int j = tid; j < 8 * 1024 + 512; j += 512) {
        int node, tok, k0; ushort* dst;
        if (j < 8192) {
            const int p = j >> 10, t = (j >> 6) & 15, l = j & 63;
            const int mrow = l & 31;
            node = 2 * p + (mrow >> 4);
            tok = mrow & 15;
            k0 = t * 16 + ((l >> 5) << 3);
            dst = &U.fragAll[(size_t)j * 8];
        } else {
            const int j2 = j - 8192;
            const int ks = j2 >> 6, l = j2 & 63;
            node = 16;
            tok = l & 15;
            k0 = ks * 32 + ((l >> 4) << 3);
            dst = &frag16[(size_t)j2 * 8];
        }
        const u32x4 gU = *(const u32x4*)&g_bf[tok][k0];
        const u32x4 sU = *(const u32x4*)&S_bf[node][k0];
        u32x4 uu;
#pragma unroll
        for (int i = 0; i < 4; ++i) {
            union { uint u; float f; } gl, gh, sl2, sh;
            gl.u = gU[i] << 16;  gh.u = gU[i] & 0xffff0000u;
            sl2.u = sU[i] << 16; sh.u = sU[i] & 0xffff0000u;
            uu[i] = pkbf(fmaxf(gl.f + sl2.f, 0.f), fmaxf(gh.f + sh.f, 0.f));
        }
        *(u32x4*)dst = uu;
    }
    __syncthreads();   // frags ready; read-only below

    // ---- phase C consume: pairs via 32x32x16, node16 via 16x16x32; barrier-free ----
    f32x16 accp[8];
#pragma unroll
    for (int p = 0; p < 8; ++p)
#pragma unroll
        for (int c2 = 0; c2 < 16; ++c2) accp[p][c2] = 0.f;

    s16x8 bW;
    loadB32<SWZ>(W2X, W2, w, 0, lane, bW);
#pragma unroll 1
    for (int t = 0; t < 16; ++t) {
        const s16x8 bcur = bW;
        if (t < 15) loadB32<SWZ>(W2X, W2, w, t + 1, lane, bW);
        __builtin_amdgcn_s_setprio(1);
#pragma unroll
        for (int p = 0; p < 8; ++p) {
            const s16x8 ah = *(const s16x8*)&U.fragAll[(size_t)((p * 16 + t) * 64 + lane) * 8];
            accp[p] = MFMA32(ah, bcur, accp[p]);
        }
        __builtin_amdgcn_s_setprio(0);
    }
    f32x4 a16[2];
    a16[0] = (f32x4){0.f, 0.f, 0.f, 0.f};
    a16[1] = (f32x4){0.f, 0.f, 0.f, 0.f};
#pragma unroll 1
    for (int ks = 0; ks < 8; ++ks) {
        s16x8 bh0, bh1;
        loadBH<SWZ>(W2H, W2, 8, 2 * w,     ks, lane, bh0);
        loadBH<SWZ>(W2H, W2, 8, 2 * w + 1, ks, lane, bh1);
        const s16x8 ah = *(const s16x8*)&frag16[(size_t)(ks * 64 + lane) * 8];
        a16[0] = MFMA16(ah, bh0, a16[0]);
        a16[1] = MFMA16(ah, bh1, a16[1]);
    }
    __syncthreads();   // all frag reads done before part (aliases fragAll head)

    // ---- align node-16 z to the 32-wide layout: slot s -> (token, this lane's d) ----
    // pair-slot s on lane l: token = (s&3)+8*(s>>2)+4*(l>>5); src 16x16 lane = (l&15)+32*(s>>2)+16*(l>>5)
    float z16v[8];
#pragma unroll
    for (int s = 0; s < 8; ++s) {
        const int srcl = (lane & 15) + 32 * (s >> 2) + 16 * (lane >> 5);
        const float v0 = __shfl(a16[0][s & 3], srcl, 64);
        const float v1 = __shfl(a16[1][s & 3], srcl, 64);
        z16v[s] = ((lane >> 4) & 1) ? v1 : v0;
    }

    // ---- phase E: y2 = relu(Ad2 @ z); score = y2 . Wp; masked scan + pair butterfly ----
    const float wp = Wp[w * 32 + (lane & 31)];
    const bool b0 = (lane & 1) != 0;
#pragma unroll
    for (int p8 = 0; p8 < 8; ++p8) {
        float v2[2][8];
#pragma unroll
        for (int j2 = 0; j2 < 2; ++j2) {
            const int e = 2 * p8 + j2;
            float ze[8];
#pragma unroll
            for (int s = 0; s < 8; ++s) ze[s] = 0.f;
#pragma unroll
            for (int m = 0; m < 16; ++m) {
                if (msk[e] & (1u << m)) {          // SGPR test -> scalar branch
                    const float av = Ad_l[e * NN + m];
#pragma unroll
                    for (int s = 0; s < 8; ++s)
                        ze[s] = fmaf(av, accp[m >> 1][8 * (m & 1) + s], ze[s]);
                }
            }
            if (msk[e] & (1u << 16)) {
                const float av = Ad_l[e * NN + 16];
#pragma unroll
                for (int s = 0; s < 8; ++s) ze[s] = fmaf(av, z16v[s], ze[s]);
            }
#pragma unroll
            for (int s = 0; s < 8; ++s) v2[j2][s] = fmaxf(ze[s], 0.f) * wp;
        }
        // merge e-pair over lane bit0, then reduce d over lane bits 1..4
        float wv[8];
#pragma unroll
        for (int s = 0; s < 8; ++s) {
            const float keep = b0 ? v2[1][s] : v2[0][s];
            const float send = b0 ? v2[0][s] : v2[1][s];
            wv[s] = keep + __shfl_xor(send, 1, 64);
        }
#pragma unroll
        for (int s = 0; s < 8; ++s) wv[s] += __shfl_xor(wv[s], 2, 64);
#pragma unroll
        for (int s = 0; s < 8; ++s) wv[s] += __shfl_xor(wv[s], 4, 64);
#pragma unroll
        for (int s = 0; s < 8; ++s) wv[s] += __shfl_xor(wv[s], 8, 64);
#pragma unroll
        for (int s = 0; s < 8; ++s) wv[s] += __shfl_xor(wv[s], 16, 64);
        if ((lane & 30) == 0) {   // lanes 0,1,32,33
            const int e = 2 * p8 + (lane & 1);
#pragma unroll
            for (int s = 0; s < 8; ++s) {
                const int tok = (s & 3) + 8 * (s >> 2) + 4 * (lane >> 5);
                U.part[tok][e][w] = wv[s];
            }
        }
    }
    __syncthreads();
    if (tid < 256) {
        const int t = tid >> 4, e = tid & 15;
        float s2 = 0.f;
#pragma unroll
        for (int q = 0; q < 8; ++q) s2 += U.part[t][e][q];
        out[(t0 + t) * NE + e] = s2;
    }
}

extern "C" void kernel_launch(void* const* d_in, const int* in_sizes, int n_in,
                              void* d_out, int out_size, void* d_ws, size_t ws_size,
                              hipStream_t stream) {
    const float* x   = (const float*)d_in[0];
    const float* X   = (const float*)d_in[1];
    const float* Wm  = (const float*)d_in[2];
    const float* Wst = (const float*)d_in[3];
    const float* Wc  = (const float*)d_in[4];
    const float* Wp  = (const float*)d_in[5];
    const float* adj = (const float*)d_in[6];
    float* out = (float*)d_out;
    float* ws  = (float*)d_ws;
    const float* W1 = Wc;
    const float* W2 = Wc + DG * DG;

    if (ws_size >= (size_t)WS_NEED) {
        k_se1<<<16 + 224, 512, 0, stream>>>(X, Wst, W1, Wm, W2, ws);
        k_se2<<<18, 256, 0, stream>>>(adj, ws);
        k_main<true><<<NTOK / TB, 512, 0, stream>>>(x, Wm, W1, W2, Wp, ws, out);
    } else {
        k_se1<<<16, 512, 0, stream>>>(X, Wst, W1, Wm, W2, ws);
        k_se2<<<18, 256, 0, stream>>>(adj, ws);
        k_main<false><<<NTOK / TB, 512, 0, stream>>>(x, Wm, W1, W2, Wp, ws, out);
    }
}